// Round 1
// baseline (2986.502 us; speedup 1.0000x reference)
//
#include <hip/hip_runtime.h>
#include <hip/hip_bf16.h>

#define N_NODES 100000
#define N_EDGES 1600000
#define NFEAT 256
#define NHID 128
#define NCLASS 8

// ---------------------------------------------------------------------------
// K1: in-degree histogram over edge dst (self-loop added later as +1)
__global__ __launch_bounds__(256) void degree_kernel(const int* __restrict__ edst,
                                                     int* __restrict__ deg, int nE) {
    int e = blockIdx.x * 256 + threadIdx.x;
    if (e < nE) atomicAdd(&deg[edst[e]], 1);
}

// K2: dinv = rsqrt(deg + 1)   (deg>=1 incl. self-loop, so no zero guard needed)
__global__ __launch_bounds__(256) void dinv_kernel(const int* __restrict__ deg,
                                                   float* __restrict__ dinv, int n) {
    int i = blockIdx.x * 256 + threadIdx.x;
    if (i < n) dinv[i] = rsqrtf((float)(deg[i] + 1));
}

// ---------------------------------------------------------------------------
// K3: H[N,128] = X[N,256] @ W[256,128], fp32 register-tiled.
// tile 64 rows x 128 cols, BK=16, 256 threads, 8x4 acc per thread.
__global__ __launch_bounds__(256) void gemm1_kernel(const float* __restrict__ X,
                                                    const float* __restrict__ W,
                                                    float* __restrict__ H, int nrows) {
    __shared__ float As[16][64];    // [k][row] (transposed A tile)
    __shared__ float Bs[16][128];   // [k][col]

    const int tid  = threadIdx.x;
    const int row0 = blockIdx.x * 64;

    const int tcol = (tid & 31) * 4;   // 0..124
    const int trow = (tid >> 5) * 8;   // 0..56

    // A-load mapping: one float4 per thread
    const int arow = tid >> 2;         // 0..63
    const int akq  = (tid & 3) * 4;    // 0,4,8,12
    // B-load mapping: two float4 per thread
    const int bk   = tid >> 5;         // 0..7
    const int bcol = (tid & 31) * 4;   // 0..124

    float acc[8][4] = {};

    for (int k0 = 0; k0 < NFEAT; k0 += 16) {
        // stage global loads into registers first
        int grow = row0 + arow;
        float4 av = make_float4(0.f, 0.f, 0.f, 0.f);
        if (grow < nrows) av = *(const float4*)&X[(long)grow * NFEAT + k0 + akq];
        float4 bv0 = *(const float4*)&W[(k0 + bk) * NHID + bcol];
        float4 bv1 = *(const float4*)&W[(k0 + bk + 8) * NHID + bcol];

        __syncthreads();   // previous iteration done reading LDS
        As[akq + 0][arow] = av.x;
        As[akq + 1][arow] = av.y;
        As[akq + 2][arow] = av.z;
        As[akq + 3][arow] = av.w;
        *(float4*)&Bs[bk][bcol]     = bv0;
        *(float4*)&Bs[bk + 8][bcol] = bv1;
        __syncthreads();

        #pragma unroll
        for (int kk = 0; kk < 16; kk++) {
            float b[4], a0[4], a1[4];
            *(float4*)b  = *(const float4*)&Bs[kk][tcol];
            *(float4*)a0 = *(const float4*)&As[kk][trow];
            *(float4*)a1 = *(const float4*)&As[kk][trow + 4];
            #pragma unroll
            for (int i = 0; i < 4; i++) {
                acc[i][0] += a0[i] * b[0];
                acc[i][1] += a0[i] * b[1];
                acc[i][2] += a0[i] * b[2];
                acc[i][3] += a0[i] * b[3];
            }
            #pragma unroll
            for (int i = 0; i < 4; i++) {
                acc[4 + i][0] += a1[i] * b[0];
                acc[4 + i][1] += a1[i] * b[1];
                acc[4 + i][2] += a1[i] * b[2];
                acc[4 + i][3] += a1[i] * b[3];
            }
        }
    }

    #pragma unroll
    for (int i = 0; i < 8; i++) {
        int r = row0 + trow + i;
        if (r < nrows) *(float4*)&H[(long)r * NHID + tcol] = *(const float4*)acc[i];
    }
}

// ---------------------------------------------------------------------------
// K4: agg[i][f] = H[i][f]*dinv[i]^2 + b1[f]   (self-loop term + bias init)
__global__ __launch_bounds__(256) void agg_init_kernel(const float* __restrict__ H,
                                                       const float* __restrict__ dinv,
                                                       const float* __restrict__ b1,
                                                       float* __restrict__ agg, int n) {
    int idx = blockIdx.x * 256 + threadIdx.x;     // over n*32 (float4 granules)
    if (idx >= n * 32) return;
    int i = idx >> 5;
    int q = (idx & 31) * 4;
    float di = dinv[i];
    float d2 = di * di;
    float4 hv = *(const float4*)&H[(long)i * NHID + q];
    float4 bv = *(const float4*)&b1[q];
    float4 r;
    r.x = hv.x * d2 + bv.x;
    r.y = hv.y * d2 + bv.y;
    r.z = hv.z * d2 + bv.z;
    r.w = hv.w * d2 + bv.w;
    *(float4*)&agg[(long)i * NHID + q] = r;
}

// ---------------------------------------------------------------------------
// K5: edge scatter: agg[dst] += H[src] * dinv[src]*dinv[dst]
// one thread per (edge, float4-granule): E*32 threads, 4 atomics each.
__global__ __launch_bounds__(256) void scatter_kernel(const float* __restrict__ H,
                                                      const int* __restrict__ esrc,
                                                      const int* __restrict__ edst,
                                                      const float* __restrict__ dinv,
                                                      float* __restrict__ agg, int nE) {
    long idx = (long)blockIdx.x * 256 + threadIdx.x;
    if (idx >= (long)nE * 32) return;
    int e = (int)(idx >> 5);
    int q = ((int)idx & 31) * 4;
    int s = esrc[e];
    int d = edst[e];
    float nrm = dinv[s] * dinv[d];
    float4 hv = *(const float4*)&H[(long)s * NHID + q];
    float* base = &agg[(long)d * NHID + q];
    atomicAdd(base + 0, hv.x * nrm);
    atomicAdd(base + 1, hv.y * nrm);
    atomicAdd(base + 2, hv.z * nrm);
    atomicAdd(base + 3, hv.w * nrm);
}

// ---------------------------------------------------------------------------
// K6: Out[N,8] = agg[N,128] @ Wfc[128,8] + bfc
__global__ __launch_bounds__(256) void gemm2_kernel(const float* __restrict__ A,
                                                    const float* __restrict__ Wfc,
                                                    const float* __restrict__ bfc,
                                                    float* __restrict__ Out, int nrows) {
    __shared__ float Ws[NHID * NCLASS];
    __shared__ float bs[NCLASS];
    int tid = threadIdx.x;
    for (int i = tid; i < NHID * NCLASS; i += 256) Ws[i] = Wfc[i];
    if (tid < NCLASS) bs[tid] = bfc[tid];
    __syncthreads();

    int row = blockIdx.x * 32 + (tid >> 3);
    int c   = tid & 7;
    if (row >= nrows) return;

    const float* arow = A + (long)row * NHID;
    float acc = 0.f;
    #pragma unroll
    for (int f = 0; f < NHID; f += 4) {
        float4 a = *(const float4*)&arow[f];
        acc += a.x * Ws[(f + 0) * NCLASS + c];
        acc += a.y * Ws[(f + 1) * NCLASS + c];
        acc += a.z * Ws[(f + 2) * NCLASS + c];
        acc += a.w * Ws[(f + 3) * NCLASS + c];
    }
    Out[(long)row * NCLASS + c] = acc + bs[c];
}

// ---------------------------------------------------------------------------
extern "C" void kernel_launch(void* const* d_in, const int* in_sizes, int n_in,
                              void* d_out, int out_size, void* d_ws, size_t ws_size,
                              hipStream_t stream) {
    const float* x    = (const float*)d_in[0];   // [N, 256]
    const int*   eidx = (const int*)d_in[1];     // [2, E] flattened
    const float* W1   = (const float*)d_in[2];   // [256, 128]
    const float* b1   = (const float*)d_in[3];   // [128]
    const float* Wfc  = (const float*)d_in[4];   // [128, 8]
    const float* bfc  = (const float*)d_in[5];   // [8]
    float* out = (float*)d_out;

    const int N = N_NODES;
    const int E = in_sizes[1] / 2;               // 1600000

    const int* esrc = eidx;
    const int* edst = eidx + E;

    // workspace layout
    float* h    = (float*)d_ws;                  // N*128 floats
    float* agg  = h + (long)N * NHID;            // N*128 floats
    int*   deg  = (int*)(agg + (long)N * NHID);  // N ints
    float* dinv = (float*)(deg + N);             // N floats

    hipMemsetAsync(deg, 0, (size_t)N * sizeof(int), stream);

    degree_kernel<<<(E + 255) / 256, 256, 0, stream>>>(edst, deg, E);
    dinv_kernel<<<(N + 255) / 256, 256, 0, stream>>>(deg, dinv, N);
    gemm1_kernel<<<(N + 63) / 64, 256, 0, stream>>>(x, W1, h, N);
    agg_init_kernel<<<(N * 32 + 255) / 256, 256, 0, stream>>>(h, dinv, b1, agg, N);
    {
        long total = (long)E * 32;
        int blocks = (int)((total + 255) / 256);
        scatter_kernel<<<blocks, 256, 0, stream>>>(h, esrc, edst, dinv, agg, E);
    }
    gemm2_kernel<<<(N + 31) / 32, 256, 0, stream>>>(agg, Wfc, bfc, out, N);
}

// Round 2
// 522.826 us; speedup vs baseline: 5.7122x; 5.7122x over previous
//
#include <hip/hip_runtime.h>
#include <hip/hip_bf16.h>

#define N_NODES 100000
#define N_EDGES 1600000
#define NFEAT 256
#define NHID 128
#define NCLASS 8

// ---------------------------------------------------------------------------
// K1: in-degree histogram over edge dst (self-loop handled analytically later)
__global__ __launch_bounds__(256) void degree_kernel(const int* __restrict__ edst,
                                                     int* __restrict__ deg, int nE) {
    int e = blockIdx.x * 256 + threadIdx.x;
    if (e < nE) atomicAdd(&deg[edst[e]], 1);
}

// K2: dinv = rsqrt(deg + 1)
__global__ __launch_bounds__(256) void dinv_kernel(const int* __restrict__ deg,
                                                   float* __restrict__ dinv, int n) {
    int i = blockIdx.x * 256 + threadIdx.x;
    if (i < n) dinv[i] = rsqrtf((float)(deg[i] + 1));
}

// ---------------------------------------------------------------------------
// Exclusive prefix sum of deg -> rowptr. 1024 elements per block.
__global__ __launch_bounds__(256) void scan1_kernel(const int* __restrict__ deg,
                                                    int* __restrict__ rowptr,
                                                    int* __restrict__ bsums, int n) {
    __shared__ int ss[256];
    int tid = threadIdx.x;
    int base = blockIdx.x * 1024 + tid * 4;
    int v0 = (base + 0 < n) ? deg[base + 0] : 0;
    int v1 = (base + 1 < n) ? deg[base + 1] : 0;
    int v2 = (base + 2 < n) ? deg[base + 2] : 0;
    int v3 = (base + 3 < n) ? deg[base + 3] : 0;
    int tsum = v0 + v1 + v2 + v3;
    ss[tid] = tsum;
    __syncthreads();
    for (int off = 1; off < 256; off <<= 1) {
        int t = (tid >= off) ? ss[tid - off] : 0;
        __syncthreads();
        ss[tid] += t;
        __syncthreads();
    }
    int ex = ss[tid] - tsum;   // exclusive within block
    if (base + 0 < n) rowptr[base + 0] = ex;
    if (base + 1 < n) rowptr[base + 1] = ex + v0;
    if (base + 2 < n) rowptr[base + 2] = ex + v0 + v1;
    if (base + 3 < n) rowptr[base + 3] = ex + v0 + v1 + v2;
    if (tid == 255) bsums[blockIdx.x] = ss[255];
}

__global__ void scan2_kernel(int* __restrict__ bsums, int nb) {
    if (threadIdx.x == 0 && blockIdx.x == 0) {
        int acc = 0;
        for (int i = 0; i < nb; i++) { int t = bsums[i]; bsums[i] = acc; acc += t; }
    }
}

__global__ __launch_bounds__(256) void scan3_kernel(int* __restrict__ rowptr,
                                                    const int* __restrict__ bsums, int n) {
    int i = blockIdx.x * 256 + threadIdx.x;
    if (i < n) rowptr[i] += bsums[blockIdx.x >> 2];   // 1024 elems per scan1 block
}

// ---------------------------------------------------------------------------
// Placement: group edge srcs by dst (unordered within group — fp32 sum commutes
// within tolerance, same as the atomic version that passed).
__global__ __launch_bounds__(256) void place_kernel(const int* __restrict__ esrc,
                                                    const int* __restrict__ edst,
                                                    const int* __restrict__ rowptr,
                                                    int* __restrict__ cursor,
                                                    int* __restrict__ ebuf, int nE) {
    int e = blockIdx.x * 256 + threadIdx.x;
    if (e >= nE) return;
    int d = edst[e];
    int pos = rowptr[d] + atomicAdd(&cursor[d], 1);
    ebuf[pos] = esrc[e];
}

// ---------------------------------------------------------------------------
// K3: Hs[N,128] = (X[N,256] @ W[256,128]) * dinv[row]  — fp32 register-tiled.
__global__ __launch_bounds__(256) void gemm1_kernel(const float* __restrict__ X,
                                                    const float* __restrict__ W,
                                                    const float* __restrict__ dinv,
                                                    float* __restrict__ Hs, int nrows) {
    __shared__ float As[16][64];    // [k][row]
    __shared__ float Bs[16][128];   // [k][col]

    const int tid  = threadIdx.x;
    const int row0 = blockIdx.x * 64;

    const int tcol = (tid & 31) * 4;
    const int trow = (tid >> 5) * 8;

    const int arow = tid >> 2;
    const int akq  = (tid & 3) * 4;
    const int bk   = tid >> 5;
    const int bcol = (tid & 31) * 4;

    float acc[8][4] = {};

    for (int k0 = 0; k0 < NFEAT; k0 += 16) {
        int grow = row0 + arow;
        float4 av = make_float4(0.f, 0.f, 0.f, 0.f);
        if (grow < nrows) av = *(const float4*)&X[(long)grow * NFEAT + k0 + akq];
        float4 bv0 = *(const float4*)&W[(k0 + bk) * NHID + bcol];
        float4 bv1 = *(const float4*)&W[(k0 + bk + 8) * NHID + bcol];

        __syncthreads();
        As[akq + 0][arow] = av.x;
        As[akq + 1][arow] = av.y;
        As[akq + 2][arow] = av.z;
        As[akq + 3][arow] = av.w;
        *(float4*)&Bs[bk][bcol]     = bv0;
        *(float4*)&Bs[bk + 8][bcol] = bv1;
        __syncthreads();

        #pragma unroll
        for (int kk = 0; kk < 16; kk++) {
            float b[4], a0[4], a1[4];
            *(float4*)b  = *(const float4*)&Bs[kk][tcol];
            *(float4*)a0 = *(const float4*)&As[kk][trow];
            *(float4*)a1 = *(const float4*)&As[kk][trow + 4];
            #pragma unroll
            for (int i = 0; i < 4; i++) {
                acc[i][0] += a0[i] * b[0];
                acc[i][1] += a0[i] * b[1];
                acc[i][2] += a0[i] * b[2];
                acc[i][3] += a0[i] * b[3];
                acc[4 + i][0] += a1[i] * b[0];
                acc[4 + i][1] += a1[i] * b[1];
                acc[4 + i][2] += a1[i] * b[2];
                acc[4 + i][3] += a1[i] * b[3];
            }
        }
    }

    #pragma unroll
    for (int i = 0; i < 8; i++) {
        int r = row0 + trow + i;
        if (r < nrows) {
            float dv = dinv[r];
            float4 o;
            o.x = acc[i][0] * dv; o.y = acc[i][1] * dv;
            o.z = acc[i][2] * dv; o.w = acc[i][3] * dv;
            *(float4*)&Hs[(long)r * NHID + tcol] = o;
        }
    }
}

// ---------------------------------------------------------------------------
// K4: fused gather + bias + fc.  One wave per node (grid-stride).
// Lane l holds features {2l, 2l+1}.  out_row = dinv[d]*(Hs[d] + sum Hs[s]) + b1
// then out = row @ Wfc + bfc via shfl_xor butterfly.
__global__ __launch_bounds__(256) void gather_fc_kernel(const float* __restrict__ Hs,
                                                        const int* __restrict__ ebuf,
                                                        const int* __restrict__ rowptr,
                                                        const int* __restrict__ deg,
                                                        const float* __restrict__ dinv,
                                                        const float* __restrict__ b1,
                                                        const float* __restrict__ Wfc,
                                                        const float* __restrict__ bfc,
                                                        float* __restrict__ out, int n) {
    const int lane = threadIdx.x & 63;
    const int wid  = (blockIdx.x * 256 + threadIdx.x) >> 6;
    const int nw   = (gridDim.x * 256) >> 6;

    // per-lane constants
    float w0[8], w1[8];
    #pragma unroll
    for (int c = 0; c < 8; c++) {
        w0[c] = Wfc[(2 * lane) * NCLASS + c];
        w1[c] = Wfc[(2 * lane + 1) * NCLASS + c];
    }
    const float bl0 = b1[2 * lane];
    const float bl1 = b1[2 * lane + 1];
    const float bb  = (lane < NCLASS) ? bfc[lane] : 0.f;

    for (int node = wid; node < n; node += nw) {
        const int start = rowptr[node];
        const int cnt   = deg[node];

        float2 acc = *(const float2*)&Hs[(long)node * NHID + 2 * lane];  // self-loop

        for (int e0 = 0; e0 < cnt; e0 += 64) {
            int m = cnt - e0; if (m > 64) m = 64;
            int sv = (lane < m) ? ebuf[start + e0 + lane] : 0;
            for (int j = 0; j < m; j++) {
                int sj = __shfl(sv, j);
                float2 hv = *(const float2*)&Hs[(long)sj * NHID + 2 * lane];
                acc.x += hv.x;
                acc.y += hv.y;
            }
        }

        const float dd = dinv[node];
        const float r0 = acc.x * dd + bl0;
        const float r1 = acc.y * dd + bl1;

        float t[8];
        #pragma unroll
        for (int c = 0; c < 8; c++) t[c] = r0 * w0[c] + r1 * w1[c];
        #pragma unroll
        for (int off = 32; off >= 1; off >>= 1) {
            #pragma unroll
            for (int c = 0; c < 8; c++) t[c] += __shfl_xor(t[c], off);
        }
        if (lane < NCLASS) out[(long)node * NCLASS + lane] = t[lane] + bb;
    }
}

// ---------------------------------------------------------------------------
extern "C" void kernel_launch(void* const* d_in, const int* in_sizes, int n_in,
                              void* d_out, int out_size, void* d_ws, size_t ws_size,
                              hipStream_t stream) {
    const float* x    = (const float*)d_in[0];   // [N, 256]
    const int*   eidx = (const int*)d_in[1];     // [2, E]
    const float* W1   = (const float*)d_in[2];   // [256, 128]
    const float* b1   = (const float*)d_in[3];   // [128]
    const float* Wfc  = (const float*)d_in[4];   // [128, 8]
    const float* bfc  = (const float*)d_in[5];   // [8]
    float* out = (float*)d_out;

    const int N = N_NODES;
    const int E = in_sizes[1] / 2;

    const int* esrc = eidx;
    const int* edst = eidx + E;

    // workspace layout (~59 MB)
    float* Hs     = (float*)d_ws;                      // N*128 floats
    int*   deg    = (int*)(Hs + (long)N * NHID);       // N
    int*   cursor = deg + N;                           // N (contiguous with deg for one memset)
    int*   rowptr = cursor + N;                        // N
    int*   bsums  = rowptr + N;                        // 128
    float* dinv   = (float*)(bsums + 128);             // N
    int*   ebuf   = (int*)(dinv + N);                  // E

    hipMemsetAsync(deg, 0, (size_t)(2 * N) * sizeof(int), stream);  // deg + cursor

    degree_kernel<<<(E + 255) / 256, 256, 0, stream>>>(edst, deg, E);
    dinv_kernel<<<(N + 255) / 256, 256, 0, stream>>>(deg, dinv, N);

    int nb = (N + 1023) / 1024;
    scan1_kernel<<<nb, 256, 0, stream>>>(deg, rowptr, bsums, N);
    scan2_kernel<<<1, 64, 0, stream>>>(bsums, nb);
    scan3_kernel<<<(N + 255) / 256, 256, 0, stream>>>(rowptr, bsums, N);

    place_kernel<<<(E + 255) / 256, 256, 0, stream>>>(esrc, edst, rowptr, cursor, ebuf, E);

    gemm1_kernel<<<(N + 63) / 64, 256, 0, stream>>>(x, W1, dinv, Hs, N);

    gather_fc_kernel<<<4096, 256, 0, stream>>>(Hs, ebuf, rowptr, deg, dinv,
                                               b1, Wfc, bfc, out, N);
}

// Round 3
// 442.021 us; speedup vs baseline: 6.7565x; 1.1828x over previous
//
#include <hip/hip_runtime.h>
#include <hip/hip_bf16.h>

#define N_NODES 100000
#define N_EDGES 1600000
#define NFEAT 256
#define NHID 128
#define NCLASS 8

// ---------------------------------------------------------------------------
// K1: in-degree histogram over edge dst (self-loop handled analytically)
__global__ __launch_bounds__(256) void degree_kernel(const int* __restrict__ edst,
                                                     int* __restrict__ deg, int nE) {
    int e = blockIdx.x * 256 + threadIdx.x;
    if (e < nE) atomicAdd(&deg[edst[e]], 1);
}

// K2: dinv = rsqrt(deg + 1)
__global__ __launch_bounds__(256) void dinv_kernel(const int* __restrict__ deg,
                                                   float* __restrict__ dinv, int n) {
    int i = blockIdx.x * 256 + threadIdx.x;
    if (i < n) dinv[i] = rsqrtf((float)(deg[i] + 1));
}

// ---------------------------------------------------------------------------
// Exclusive prefix sum of deg -> rowptr. 1024 elements per block.
__global__ __launch_bounds__(256) void scan1_kernel(const int* __restrict__ deg,
                                                    int* __restrict__ rowptr,
                                                    int* __restrict__ bsums, int n) {
    __shared__ int ss[256];
    int tid = threadIdx.x;
    int base = blockIdx.x * 1024 + tid * 4;
    int v0 = (base + 0 < n) ? deg[base + 0] : 0;
    int v1 = (base + 1 < n) ? deg[base + 1] : 0;
    int v2 = (base + 2 < n) ? deg[base + 2] : 0;
    int v3 = (base + 3 < n) ? deg[base + 3] : 0;
    int tsum = v0 + v1 + v2 + v3;
    ss[tid] = tsum;
    __syncthreads();
    for (int off = 1; off < 256; off <<= 1) {
        int t = (tid >= off) ? ss[tid - off] : 0;
        __syncthreads();
        ss[tid] += t;
        __syncthreads();
    }
    int ex = ss[tid] - tsum;
    if (base + 0 < n) rowptr[base + 0] = ex;
    if (base + 1 < n) rowptr[base + 1] = ex + v0;
    if (base + 2 < n) rowptr[base + 2] = ex + v0 + v1;
    if (base + 3 < n) rowptr[base + 3] = ex + v0 + v1 + v2;
    if (tid == 255) bsums[blockIdx.x] = ss[255];
}

__global__ void scan2_kernel(int* __restrict__ bsums, int nb) {
    if (threadIdx.x == 0 && blockIdx.x == 0) {
        int acc = 0;
        for (int i = 0; i < nb; i++) { int t = bsums[i]; bsums[i] = acc; acc += t; }
    }
}

__global__ __launch_bounds__(256) void scan3_kernel(int* __restrict__ rowptr,
                                                    const int* __restrict__ bsums, int n) {
    int i = blockIdx.x * 256 + threadIdx.x;
    if (i < n) rowptr[i] += bsums[blockIdx.x >> 2];
}

// ---------------------------------------------------------------------------
// Placement: group edge srcs by dst (unordered within group; fp32 sum order
// tolerance already validated by previous rounds).
__global__ __launch_bounds__(256) void place_kernel(const int* __restrict__ esrc,
                                                    const int* __restrict__ edst,
                                                    const int* __restrict__ rowptr,
                                                    int* __restrict__ cursor,
                                                    int* __restrict__ ebuf, int nE) {
    int e = blockIdx.x * 256 + threadIdx.x;
    if (e >= nE) return;
    int d = edst[e];
    int pos = rowptr[d] + atomicAdd(&cursor[d], 1);
    ebuf[pos] = esrc[e];
}

// ---------------------------------------------------------------------------
// Kc: WcT[8][256] = (W1 @ Wfc)^T  and  cvec[8] = b1 @ Wfc + bfc.
// One block, 256 threads (thread = feature f).
__global__ __launch_bounds__(256) void wc_kernel(const float* __restrict__ W1,
                                                 const float* __restrict__ b1,
                                                 const float* __restrict__ Wfc,
                                                 const float* __restrict__ bfc,
                                                 float* __restrict__ WcT,
                                                 float* __restrict__ cvec) {
    __shared__ float wfs[NHID * NCLASS];
    __shared__ float bs[NHID];
    int tid = threadIdx.x;
    for (int i = tid; i < NHID * NCLASS; i += 256) wfs[i] = Wfc[i];
    if (tid < NHID) bs[tid] = b1[tid];
    __syncthreads();

    float acc[NCLASS] = {};
    for (int h = 0; h < NHID; h++) {
        float w = W1[tid * NHID + h];
        #pragma unroll
        for (int c = 0; c < NCLASS; c++) acc[c] += w * wfs[h * NCLASS + c];
    }
    #pragma unroll
    for (int c = 0; c < NCLASS; c++) WcT[c * NFEAT + tid] = acc[c];

    if (tid < NCLASS) {
        float a = bfc[tid];
        for (int h = 0; h < NHID; h++) a += bs[h] * wfs[h * NCLASS + tid];
        cvec[tid] = a;
    }
}

// ---------------------------------------------------------------------------
// Kz: Zs[i][c] = dot(X[i], WcT[c]) * dinv[i].  Thread per (row, class).
// X streamed once (102 MB -> HBM-bound); WcT (8 KB) L1-resident.
__global__ __launch_bounds__(256) void z_kernel(const float* __restrict__ X,
                                                const float* __restrict__ WcT,
                                                const float* __restrict__ dinv,
                                                float* __restrict__ Zs, int n) {
    int idx = blockIdx.x * 256 + threadIdx.x;
    if (idx >= n * NCLASS) return;
    int row = idx >> 3;
    int c   = idx & 7;
    const float* xr = X + (long)row * NFEAT;
    const float* wr = WcT + c * NFEAT;
    float acc = 0.f;
    #pragma unroll 8
    for (int f = 0; f < NFEAT; f += 4) {
        float4 x = *(const float4*)&xr[f];
        float4 w = *(const float4*)&wr[f];
        acc += x.x * w.x + x.y * w.y + x.z * w.z + x.w * w.w;
    }
    Zs[idx] = acc * dinv[row];
}

// ---------------------------------------------------------------------------
// Kg: out[d][c] = dinv[d] * (Zs[d][c] + sum_{s in N(d)} Zs[s][c]) + cvec[c]
// Thread per (node, class); Zs (3.2 MB) is L2-resident so the random gather
// stays on-chip.
__global__ __launch_bounds__(256) void gather_fc_kernel(const float* __restrict__ Zs,
                                                        const int* __restrict__ ebuf,
                                                        const int* __restrict__ rowptr,
                                                        const int* __restrict__ deg,
                                                        const float* __restrict__ dinv,
                                                        const float* __restrict__ cvec,
                                                        float* __restrict__ out, int n) {
    int idx = blockIdx.x * 256 + threadIdx.x;
    if (idx >= n * NCLASS) return;
    int node = idx >> 3;
    int c    = idx & 7;
    int start = rowptr[node];
    int cnt   = deg[node];
    const int* eb = ebuf + start;

    float acc = Zs[idx];   // self-loop term (already dinv[node]-scaled)
    int k = 0;
    for (; k + 1 < cnt; k += 2) {       // 2-way unroll for load ILP
        int s0 = eb[k];
        int s1 = eb[k + 1];
        acc += Zs[s0 * NCLASS + c];
        acc += Zs[s1 * NCLASS + c];
    }
    if (k < cnt) acc += Zs[eb[k] * NCLASS + c];

    out[idx] = acc * dinv[node] + cvec[c];
}

// ---------------------------------------------------------------------------
extern "C" void kernel_launch(void* const* d_in, const int* in_sizes, int n_in,
                              void* d_out, int out_size, void* d_ws, size_t ws_size,
                              hipStream_t stream) {
    const float* x    = (const float*)d_in[0];   // [N, 256]
    const int*   eidx = (const int*)d_in[1];     // [2, E]
    const float* W1   = (const float*)d_in[2];   // [256, 128]
    const float* b1   = (const float*)d_in[3];   // [128]
    const float* Wfc  = (const float*)d_in[4];   // [128, 8]
    const float* bfc  = (const float*)d_in[5];   // [8]
    float* out = (float*)d_out;

    const int N = N_NODES;
    const int E = in_sizes[1] / 2;

    const int* esrc = eidx;
    const int* edst = eidx + E;

    // workspace layout (~13 MB)
    float* Zs     = (float*)d_ws;                 // N*8
    float* dinv   = Zs + (long)N * NCLASS;        // N
    int*   deg    = (int*)(dinv + N);             // N
    int*   cursor = deg + N;                      // N (contiguous with deg: one memset)
    int*   rowptr = cursor + N;                   // N
    int*   bsums  = rowptr + N;                   // 128
    float* cvec   = (float*)(bsums + 128);        // 8
    float* WcT    = cvec + 8;                     // 8*256
    int*   ebuf   = (int*)(WcT + NCLASS * NFEAT); // E

    hipMemsetAsync(deg, 0, (size_t)(2 * N) * sizeof(int), stream);  // deg + cursor

    degree_kernel<<<(E + 255) / 256, 256, 0, stream>>>(edst, deg, E);
    dinv_kernel<<<(N + 255) / 256, 256, 0, stream>>>(deg, dinv, N);

    int nb = (N + 1023) / 1024;
    scan1_kernel<<<nb, 256, 0, stream>>>(deg, rowptr, bsums, N);
    scan2_kernel<<<1, 64, 0, stream>>>(bsums, nb);
    scan3_kernel<<<(N + 255) / 256, 256, 0, stream>>>(rowptr, bsums, N);

    place_kernel<<<(E + 255) / 256, 256, 0, stream>>>(esrc, edst, rowptr, cursor, ebuf, E);

    wc_kernel<<<1, 256, 0, stream>>>(W1, b1, Wfc, bfc, WcT, cvec);

    z_kernel<<<(N * NCLASS + 255) / 256, 256, 0, stream>>>(x, WcT, dinv, Zs, N);

    gather_fc_kernel<<<(N * NCLASS + 255) / 256, 256, 0, stream>>>(
        Zs, ebuf, rowptr, deg, dinv, cvec, out, N);
}

// Round 4
// 327.403 us; speedup vs baseline: 9.1218x; 1.3501x over previous
//
#include <hip/hip_runtime.h>
#include <hip/hip_bf16.h>

#define N_NODES 100000
#define N_EDGES 1600000
#define NFEAT 256
#define NHID 128
#define NCLASS 8

// ---------------------------------------------------------------------------
// K1: degree histogram + per-edge rank capture (rank = position within dst
// bucket). 4 edges/thread, int4 loads; rank write is coalesced.
__global__ __launch_bounds__(256) void degree_rank_kernel(const int* __restrict__ edst,
                                                          int* __restrict__ deg,
                                                          int* __restrict__ rank, int nE) {
    int e4 = (blockIdx.x * 256 + threadIdx.x) * 4;
    if (e4 + 3 < nE) {
        int4 d = *(const int4*)&edst[e4];
        int r0 = atomicAdd(&deg[d.x], 1);
        int r1 = atomicAdd(&deg[d.y], 1);
        int r2 = atomicAdd(&deg[d.z], 1);
        int r3 = atomicAdd(&deg[d.w], 1);
        *(int4*)&rank[e4] = make_int4(r0, r1, r2, r3);
    } else {
        for (int e = e4; e < nE; e++)
            rank[e] = atomicAdd(&deg[edst[e]], 1);
    }
}

// ---------------------------------------------------------------------------
// Exclusive prefix sum of deg -> rowptr (1024 elems/block), dinv fused in.
__global__ __launch_bounds__(256) void scan1_kernel(const int* __restrict__ deg,
                                                    int* __restrict__ rowptr,
                                                    int* __restrict__ bsums,
                                                    float* __restrict__ dinv, int n) {
    __shared__ int ss[256];
    int tid = threadIdx.x;
    int base = blockIdx.x * 1024 + tid * 4;
    int v0 = (base + 0 < n) ? deg[base + 0] : 0;
    int v1 = (base + 1 < n) ? deg[base + 1] : 0;
    int v2 = (base + 2 < n) ? deg[base + 2] : 0;
    int v3 = (base + 3 < n) ? deg[base + 3] : 0;
    int tsum = v0 + v1 + v2 + v3;
    ss[tid] = tsum;
    __syncthreads();
    for (int off = 1; off < 256; off <<= 1) {
        int t = (tid >= off) ? ss[tid - off] : 0;
        __syncthreads();
        ss[tid] += t;
        __syncthreads();
    }
    int ex = ss[tid] - tsum;
    if (base + 0 < n) { rowptr[base + 0] = ex;                dinv[base + 0] = rsqrtf((float)(v0 + 1)); }
    if (base + 1 < n) { rowptr[base + 1] = ex + v0;           dinv[base + 1] = rsqrtf((float)(v1 + 1)); }
    if (base + 2 < n) { rowptr[base + 2] = ex + v0 + v1;      dinv[base + 2] = rsqrtf((float)(v2 + 1)); }
    if (base + 3 < n) { rowptr[base + 3] = ex + v0 + v1 + v2; dinv[base + 3] = rsqrtf((float)(v3 + 1)); }
    if (tid == 255) bsums[blockIdx.x] = ss[255];
}

__global__ void scan2_kernel(int* __restrict__ bsums, int nb) {
    if (threadIdx.x == 0 && blockIdx.x == 0) {
        int acc = 0;
        for (int i = 0; i < nb; i++) { int t = bsums[i]; bsums[i] = acc; acc += t; }
    }
}

__global__ __launch_bounds__(256) void scan3_kernel(int* __restrict__ rowptr,
                                                    const int* __restrict__ bsums, int n) {
    int i = blockIdx.x * 256 + threadIdx.x;
    if (i < n) rowptr[i] += bsums[blockIdx.x >> 2];
}

// ---------------------------------------------------------------------------
// Placement: atomic-free (rank precomputed). 4 edges/thread.
__global__ __launch_bounds__(256) void place_kernel(const int* __restrict__ esrc,
                                                    const int* __restrict__ edst,
                                                    const int* __restrict__ rank,
                                                    const int* __restrict__ rowptr,
                                                    int* __restrict__ ebuf, int nE) {
    int e4 = (blockIdx.x * 256 + threadIdx.x) * 4;
    if (e4 + 3 < nE) {
        int4 s = *(const int4*)&esrc[e4];
        int4 d = *(const int4*)&edst[e4];
        int4 r = *(const int4*)&rank[e4];
        ebuf[rowptr[d.x] + r.x] = s.x;
        ebuf[rowptr[d.y] + r.y] = s.y;
        ebuf[rowptr[d.z] + r.z] = s.z;
        ebuf[rowptr[d.w] + r.w] = s.w;
    } else {
        for (int e = e4; e < nE; e++)
            ebuf[rowptr[edst[e]] + rank[e]] = esrc[e];
    }
}

// ---------------------------------------------------------------------------
// Kc: WcT[8][256] = (W1 @ Wfc)^T  and  cvec[8] = b1 @ Wfc + bfc.
__global__ __launch_bounds__(256) void wc_kernel(const float* __restrict__ W1,
                                                 const float* __restrict__ b1,
                                                 const float* __restrict__ Wfc,
                                                 const float* __restrict__ bfc,
                                                 float* __restrict__ WcT,
                                                 float* __restrict__ cvec) {
    __shared__ float wfs[NHID * NCLASS];
    __shared__ float bs[NHID];
    int tid = threadIdx.x;
    for (int i = tid; i < NHID * NCLASS; i += 256) wfs[i] = Wfc[i];
    if (tid < NHID) bs[tid] = b1[tid];
    __syncthreads();

    float acc[NCLASS] = {};
    for (int h = 0; h < NHID; h++) {
        float w = W1[tid * NHID + h];
        #pragma unroll
        for (int c = 0; c < NCLASS; c++) acc[c] += w * wfs[h * NCLASS + c];
    }
    #pragma unroll
    for (int c = 0; c < NCLASS; c++) WcT[c * NFEAT + tid] = acc[c];

    if (tid < NCLASS) {
        float a = bfc[tid];
        for (int h = 0; h < NHID; h++) a += bs[h] * wfs[h * NCLASS + tid];
        cvec[tid] = a;
    }
}

// ---------------------------------------------------------------------------
// Kz: Zs[i][c] = dot(X[i], WcT[c]) * dinv[i].
// Wave = 8 rows; 8 lanes/row each own 32 features in 8 float4 regs (X read
// once, coalesced). WcT in LDS (8-way broadcast, conflict-free). Per class:
// 32 FMA + 3-step shfl_xor reduce over the 8-lane group.
__global__ __launch_bounds__(256) void z_kernel(const float* __restrict__ X,
                                                const float* __restrict__ WcT,
                                                const float* __restrict__ dinv,
                                                float* __restrict__ Zs, int n) {
    __shared__ float4 wlds[NCLASS * 64];    // 8 KB: wlds[c*64+g] = WcT[c][4g..4g+3]
    int tid = threadIdx.x;
    #pragma unroll
    for (int i = tid; i < NCLASS * 64; i += 256)
        wlds[i] = ((const float4*)WcT)[i];
    __syncthreads();

    const int lane = tid & 63;
    const int sub  = lane & 7;     // feature-chunk / class lane
    const int rsub = lane >> 3;    // row within 8-row group
    const int wid  = (blockIdx.x * 256 + tid) >> 6;
    const int nw   = (gridDim.x * 256) >> 6;
    const int ngroups = (n + 7) >> 3;

    for (int g = wid; g < ngroups; g += nw) {
        int row = g * 8 + rsub;
        bool ok = row < n;
        int r = ok ? row : (n - 1);
        const float4* xr = (const float4*)(X + (long)r * NFEAT);
        float4 xv[8];
        #pragma unroll
        for (int k = 0; k < 8; k++) xv[k] = xr[sub + 8 * k];

        float res = 0.f;
        #pragma unroll
        for (int c = 0; c < NCLASS; c++) {
            float s = 0.f;
            #pragma unroll
            for (int k = 0; k < 8; k++) {
                float4 w = wlds[c * 64 + sub + 8 * k];
                s += xv[k].x * w.x + xv[k].y * w.y + xv[k].z * w.z + xv[k].w * w.w;
            }
            s += __shfl_xor(s, 1);
            s += __shfl_xor(s, 2);
            s += __shfl_xor(s, 4);
            if (sub == c) res = s;
        }
        if (ok) Zs[(long)row * NCLASS + sub] = res * dinv[row];  // lane-contiguous store
    }
}

// ---------------------------------------------------------------------------
// Kg: out[d][c] = dinv[d] * (Zs[d][c] + sum_{s in N(d)} Zs[s][c]) + cvec[c]
__global__ __launch_bounds__(256) void gather_fc_kernel(const float* __restrict__ Zs,
                                                        const int* __restrict__ ebuf,
                                                        const int* __restrict__ rowptr,
                                                        const int* __restrict__ deg,
                                                        const float* __restrict__ dinv,
                                                        const float* __restrict__ cvec,
                                                        float* __restrict__ out, int n) {
    int idx = blockIdx.x * 256 + threadIdx.x;
    if (idx >= n * NCLASS) return;
    int node = idx >> 3;
    int c    = idx & 7;
    int start = rowptr[node];
    int cnt   = deg[node];
    const int* eb = ebuf + start;

    float acc = Zs[idx];   // self-loop term (already dinv[node]-scaled)
    int k = 0;
    for (; k + 3 < cnt; k += 4) {
        int s0 = eb[k], s1 = eb[k + 1], s2 = eb[k + 2], s3 = eb[k + 3];
        float a0 = Zs[s0 * NCLASS + c];
        float a1 = Zs[s1 * NCLASS + c];
        float a2 = Zs[s2 * NCLASS + c];
        float a3 = Zs[s3 * NCLASS + c];
        acc += (a0 + a1) + (a2 + a3);
    }
    for (; k < cnt; k++) acc += Zs[eb[k] * NCLASS + c];

    out[idx] = acc * dinv[node] + cvec[c];
}

// ---------------------------------------------------------------------------
extern "C" void kernel_launch(void* const* d_in, const int* in_sizes, int n_in,
                              void* d_out, int out_size, void* d_ws, size_t ws_size,
                              hipStream_t stream) {
    const float* x    = (const float*)d_in[0];   // [N, 256]
    const int*   eidx = (const int*)d_in[1];     // [2, E]
    const float* W1   = (const float*)d_in[2];   // [256, 128]
    const float* b1   = (const float*)d_in[3];   // [128]
    const float* Wfc  = (const float*)d_in[4];   // [128, 8]
    const float* bfc  = (const float*)d_in[5];   // [8]
    float* out = (float*)d_out;

    const int N = N_NODES;
    const int E = in_sizes[1] / 2;

    const int* esrc = eidx;
    const int* edst = eidx + E;

    // workspace layout (~17 MB)
    float* Zs     = (float*)d_ws;                 // N*8
    float* dinv   = Zs + (long)N * NCLASS;        // N
    int*   deg    = (int*)(dinv + N);             // N
    int*   rowptr = deg + N;                      // N
    int*   bsums  = rowptr + N;                   // 128
    float* cvec   = (float*)(bsums + 128);        // 8
    float* WcT    = cvec + 8;                     // 8*256
    int*   rank   = (int*)(WcT + NCLASS * NFEAT); // E
    int*   ebuf   = rank + E;                     // E

    hipMemsetAsync(deg, 0, (size_t)N * sizeof(int), stream);

    degree_rank_kernel<<<(E / 4 + 255) / 256, 256, 0, stream>>>(edst, deg, rank, E);

    int nb = (N + 1023) / 1024;
    scan1_kernel<<<nb, 256, 0, stream>>>(deg, rowptr, bsums, dinv, N);
    scan2_kernel<<<1, 64, 0, stream>>>(bsums, nb);
    scan3_kernel<<<(N + 255) / 256, 256, 0, stream>>>(rowptr, bsums, N);

    place_kernel<<<(E / 4 + 255) / 256, 256, 0, stream>>>(esrc, edst, rank, rowptr, ebuf, E);

    wc_kernel<<<1, 256, 0, stream>>>(W1, b1, Wfc, bfc, WcT, cvec);

    z_kernel<<<1563, 256, 0, stream>>>(x, WcT, dinv, Zs, N);

    gather_fc_kernel<<<(N * NCLASS + 255) / 256, 256, 0, stream>>>(
        Zs, ebuf, rowptr, deg, dinv, cvec, out, N);
}